// Round 2
// baseline (711.109 us; speedup 1.0000x reference)
//
#include <hip/hip_runtime.h>
#include <math.h>

#define R_ROIS 2000
#define NOBJ   21
#define NACT   27
#define HUMAN  14
#define CFEAT  512
#define HF     38
#define WF     50
#define DFEAT  (CFEAT*7*7)   // 25088
#define H1DIM  4096
#define NC     4096          // ncols of both big matvecs
#define NP1    196           // W1 row chunks (25088/128)
#define NP2    128           // W2 row chunks (4096/32)

// ---- ws layout (float offsets) ----
#define WS_KEPT   0                      // 20*4 kept boxes (feature coords, yxyx)
#define WS_FEAT   128                    // 25088
#define WS_P1     25216                  // 196*4096 partials for W1 matvec
#define WS_H1R    (WS_P1 + NP1*NC)       // 4096 (post bias+relu)
#define WS_P2     (WS_H1R + NC)          // 128*4096 partials for W2 matvec
#define WS_FC7R   (WS_P2 + NP2*NC)       // 4096
#define WS_LOC    (WS_FC7R + NC)         // 4
#define WS_ACT    (WS_LOC + 4)           // 27

// NMS with thresh 0.0 keeps exactly the top-prob box per class.
// One block per class (1..20): argmax_r softmax-prob (computed as score - logZ
// inline), then decode+clip that box. Tie-break: lowest row index (stable sort).
__global__ void k_class_top(const float* __restrict__ scores,
                            const float* __restrict__ off, const float* __restrict__ rois,
                            const int* __restrict__ imgshape, float* __restrict__ kept_box) {
    int cls = blockIdx.x + 1;  // class channel 1..20 -> label cls-1
    __shared__ float sval[256];
    __shared__ int   sidx[256];
    float best = -1e30f; int bidx = 0x7fffffff;
    for (int r = threadIdx.x; r < R_ROIS; r += 256) {
        const float* s = scores + r * NOBJ;
        float m = s[0];
        #pragma unroll
        for (int c = 1; c < NOBJ; ++c) m = fmaxf(m, s[c]);
        float sum = 0.f;
        #pragma unroll
        for (int c = 0; c < NOBJ; ++c) sum += expf(s[c] - m);
        float v = s[cls] - (m + logf(sum));   // log prob; monotonic in prob
        if (v > best) { best = v; bidx = r; }
    }
    sval[threadIdx.x] = best; sidx[threadIdx.x] = bidx;
    __syncthreads();
    for (int s = 128; s > 0; s >>= 1) {
        if (threadIdx.x < s) {
            float ov = sval[threadIdx.x + s]; int oi = sidx[threadIdx.x + s];
            if (ov > sval[threadIdx.x] ||
                (ov == sval[threadIdx.x] && oi < sidx[threadIdx.x])) {
                sval[threadIdx.x] = ov; sidx[threadIdx.x] = oi;
            }
        }
        __syncthreads();
    }
    if (threadIdx.x == 0) {
        int r = sidx[0];
        float Himg = (float)imgshape[0], Wimg = (float)imgshape[1];
        float sy = (float)HF / Himg, sx = (float)WF / Wimg;
        float y1 = rois[r*4+0]*sy, x1 = rois[r*4+1]*sx;
        float y2 = rois[r*4+2]*sy, x2 = rois[r*4+3]*sx;
        float dy = off[r*(NOBJ*4) + cls*4+0] * 0.1f;
        float dx = off[r*(NOBJ*4) + cls*4+1] * 0.1f;
        float dh = off[r*(NOBJ*4) + cls*4+2] * 0.2f;
        float dw = off[r*(NOBJ*4) + cls*4+3] * 0.2f;
        float h = y2 - y1, w = x2 - x1;
        float cy = y1 + 0.5f*h, cx = x1 + 0.5f*w;
        float cy2 = dy*h + cy, cx2 = dx*w + cx;
        float h2 = expf(dh)*h, w2 = expf(dw)*w;
        float by1 = fminf(fmaxf(cy2 - 0.5f*h2, 0.f), (float)HF);
        float bx1 = fminf(fmaxf(cx2 - 0.5f*w2, 0.f), (float)WF);
        float by2 = fminf(fmaxf(cy2 + 0.5f*h2, 0.f), (float)HF);
        float bx2 = fminf(fmaxf(cx2 + 0.5f*w2, 0.f), (float)WF);
        int l = cls - 1;
        kept_box[l*4+0] = by1; kept_box[l*4+1] = bx1;
        kept_box[l*4+2] = by2; kept_box[l*4+3] = bx2;
    }
}

// chainer RoIPooling2D on the human box (feature coords scaled AGAIN by 1/16 — quirk preserved)
__global__ void k_roipool(const float* __restrict__ x, const float* __restrict__ kept_box,
                          float* __restrict__ feat) {
    int idx = blockIdx.x * blockDim.x + threadIdx.x;
    if (idx >= DFEAT) return;
    float y1 = kept_box[HUMAN*4+0], x1 = kept_box[HUMAN*4+1];
    float y2 = kept_box[HUMAN*4+2], x2 = kept_box[HUMAN*4+3];
    int xmin = (int)rintf(x1 * 0.0625f);   // jnp.round = round-half-even = rintf
    int ymin = (int)rintf(y1 * 0.0625f);
    int xmax = (int)rintf(x2 * 0.0625f);
    int ymax = (int)rintf(y2 * 0.0625f);
    float rw = (float)max(xmax - xmin + 1, 1);
    float rh = (float)max(ymax - ymin + 1, 1);
    int c = idx / 49, rem = idx % 49, pi = rem / 7, pj = rem % 7;
    int hs  = min(max(ymin + (int)floorf((float)pi * rh / 7.f), 0), HF);
    int he  = min(max(ymin + (int)ceilf((float)(pi+1) * rh / 7.f), 0), HF);
    int wss = min(max(xmin + (int)floorf((float)pj * rw / 7.f), 0), WF);
    int we  = min(max(xmin + (int)ceilf((float)(pj+1) * rw / 7.f), 0), WF);
    float m = -1e30f;
    for (int rr = hs; rr < he; ++rr)
        for (int cc = wss; cc < we; ++cc)
            m = fmaxf(m, x[c*(HF*WF) + rr*WF + cc]);
    feat[idx] = (m <= -5e29f) ? 0.f : m;
}

// Stage A of v^T @ W (W row-major [nrows, NC=4096]).
// grid.x = row chunks of ROWS, grid.y = 2048-col tiles (2 per matvec).
// Each thread owns 2 float4 column groups (8 accumulators) -> 8 independent
// 16B loads in flight per unroll-4 step. No atomics: partials to ws.
template<int ROWS>
__global__ __launch_bounds__(256)
void k_mv_part(const float* __restrict__ W, const float* __restrict__ vin,
               float* __restrict__ part) {
    __shared__ float sv[ROWS];
    int row0 = blockIdx.x * ROWS;
    int col0 = blockIdx.y * 2048 + threadIdx.x * 4;
    for (int i = threadIdx.x; i < ROWS; i += 256) sv[i] = vin[row0 + i];
    __syncthreads();
    float a0=0.f,a1=0.f,a2=0.f,a3=0.f,b0=0.f,b1=0.f,b2=0.f,b3=0.f;
    const float4* Wv = (const float4*)W;
    long base = ((long)row0 * NC + col0) >> 2;
    #pragma unroll 4
    for (int i = 0; i < ROWS; ++i) {
        float f = sv[i];
        float4 w0 = Wv[base + (long)i * (NC/4)];
        float4 w1 = Wv[base + (long)i * (NC/4) + 256];  // +1024 cols
        a0 += f*w0.x; a1 += f*w0.y; a2 += f*w0.z; a3 += f*w0.w;
        b0 += f*w1.x; b1 += f*w1.y; b2 += f*w1.z; b3 += f*w1.w;
    }
    float4* p = (float4*)(part + (long)blockIdx.x * NC + col0);
    p[0]   = make_float4(a0, a1, a2, a3);
    p[256] = make_float4(b0, b1, b2, b3);
}

// Stage B: vout[c] = relu(sum_p part[p][c] + bias[c]); coalesced strided reads.
__global__ void k_reduce(const float* __restrict__ part, const float* __restrict__ bias,
                         float* __restrict__ vout, int nparts) {
    int c = blockIdx.x * 256 + threadIdx.x;
    float s = 0.f;
    for (int p = 0; p < nparts; ++p) s += part[(long)p * NC + c];
    vout[c] = fmaxf(s + bias[c], 0.f);
}

// small heads: 31 blocks, block k -> dot(fc7r, col k of W_loc/W_act) + bias
__global__ void k_heads(const float* __restrict__ fc7r,
                        const float* __restrict__ W_loc, const float* __restrict__ b_loc,
                        const float* __restrict__ W_act, const float* __restrict__ b_act,
                        float* __restrict__ loc_out, float* __restrict__ act_out) {
    int k = blockIdx.x;  // 0..30
    __shared__ float red[256];
    float sum = 0.f;
    if (k < 4) {
        for (int i = threadIdx.x; i < H1DIM; i += 256) sum += fc7r[i] * W_loc[i*4 + k];
    } else {
        int j = k - 4;
        for (int i = threadIdx.x; i < H1DIM; i += 256) sum += fc7r[i] * W_act[i*NACT + j];
    }
    red[threadIdx.x] = sum; __syncthreads();
    for (int s = 128; s > 0; s >>= 1) {
        if (threadIdx.x < s) red[threadIdx.x] += red[threadIdx.x + s];
        __syncthreads();
    }
    if (threadIdx.x == 0) {
        if (k < 4) loc_out[k] = red[0] + b_loc[k];
        else       act_out[k-4] = red[0] + b_act[k-4];
    }
}

// gaussian object pick over the 19 kept non-human boxes + write all 36 outputs
__global__ void k_final(const float* __restrict__ kept_box, const float* __restrict__ loc_out,
                        const float* __restrict__ act_out, const int* __restrict__ imgshape,
                        float* __restrict__ out) {
    if (threadIdx.x != 0 || blockIdx.x != 0) return;
    float hb0 = kept_box[HUMAN*4+0], hb1 = kept_box[HUMAN*4+1];
    float hb2 = kept_box[HUMAN*4+2], hb3 = kept_box[HUMAN*4+3];
    float h4w = hb3 - hb1, h4h = hb2 - hb0;
    float h4x = 0.5f * h4w, h4y = 0.5f * h4h;
    float hw = fmaxf(h4w, 1e-3f), hh = fmaxf(h4h, 1e-3f);
    float l0 = loc_out[0], l1 = loc_out[1], l2 = loc_out[2], l3 = loc_out[3];
    float muw = l3 - l1, muh = l2 - l0;
    float mux = 0.5f * muw, muy = 0.5f * muh;
    float bestg = -2.f; int bl = 0;
    for (int l = 0; l < 20; ++l) {
        if (l == HUMAN) continue;
        float b0 = kept_box[l*4+0], b1 = kept_box[l*4+1];
        float b2 = kept_box[l*4+2], b3 = kept_box[l*4+3];
        float cw = fmaxf(b3 - b1, 1e-3f), ch = fmaxf(b2 - b0, 1e-3f);
        float c0 = 0.5f * (b3 - b1), c1 = 0.5f * (b2 - b0);
        float d0 = (c0 - h4x) / hw - mux;
        float d1 = (c1 - h4y) / hh - muy;
        float d2 = logf(cw / hw) - muw;
        float d3 = logf(ch / hh) - muh;
        float g = expf(-(d0*d0 + d1*d1 + d2*d2 + d3*d3) / (2.f * 0.3f * 0.3f));
        if (g > bestg) { bestg = g; bl = l; }  // ascending l == flatten-order tie-break
    }
    float Himg = (float)imgshape[0], Wimg = (float)imgshape[1];
    float iy = Himg / (float)HF, ix = Wimg / (float)WF;
    out[0] = hb0 * iy; out[1] = hb1 * ix; out[2] = hb2 * iy; out[3] = hb3 * ix;
    out[4] = kept_box[bl*4+0] * iy; out[5] = kept_box[bl*4+1] * ix;
    out[6] = kept_box[bl*4+2] * iy; out[7] = kept_box[bl*4+3] * ix;
    for (int j = 0; j < NACT; ++j) out[8+j] = act_out[j];
    out[35] = (float)HF / Himg;
}

extern "C" void kernel_launch(void* const* d_in, const int* in_sizes, int n_in,
                              void* d_out, int out_size, void* d_ws, size_t ws_size,
                              hipStream_t stream) {
    const float* x           = (const float*)d_in[0];
    const float* pred_scores = (const float*)d_in[1];
    const float* pred_off    = (const float*)d_in[2];
    const float* rois        = (const float*)d_in[3];
    const int*   imgshape    = (const int*)d_in[4];
    const float* W1          = (const float*)d_in[5];
    const float* b1          = (const float*)d_in[6];
    const float* W2          = (const float*)d_in[7];
    const float* b2          = (const float*)d_in[8];
    const float* W_loc       = (const float*)d_in[9];
    const float* b_loc       = (const float*)d_in[10];
    const float* W_act       = (const float*)d_in[11];
    const float* b_act       = (const float*)d_in[12];
    float* out = (float*)d_out;

    float* ws   = (float*)d_ws;
    float* kept = ws + WS_KEPT;
    float* feat = ws + WS_FEAT;
    float* p1   = ws + WS_P1;
    float* h1r  = ws + WS_H1R;
    float* p2   = ws + WS_P2;
    float* fc7r = ws + WS_FC7R;
    float* loco = ws + WS_LOC;
    float* acto = ws + WS_ACT;

    k_class_top<<<20, 256, 0, stream>>>(pred_scores, pred_off, rois, imgshape, kept);
    k_roipool<<<(DFEAT + 255) / 256, 256, 0, stream>>>(x, kept, feat);
    // feat[25088] @ W1[25088,4096]: 196 row-chunks x 2 col-tiles, partials -> reduce
    k_mv_part<128><<<dim3(NP1, 2), 256, 0, stream>>>(W1, feat, p1);
    k_reduce<<<16, 256, 0, stream>>>(p1, b1, h1r, NP1);
    // h1r[4096] @ W2[4096,4096]: 128 row-chunks x 2 col-tiles
    k_mv_part<32><<<dim3(NP2, 2), 256, 0, stream>>>(W2, h1r, p2);
    k_reduce<<<16, 256, 0, stream>>>(p2, b2, fc7r, NP2);
    k_heads<<<31, 256, 0, stream>>>(fc7r, W_loc, b_loc, W_act, b_act, loco, acto);
    k_final<<<1, 64, 0, stream>>>(kept, loco, acto, imgshape, out);
}

// Round 3
// 651.465 us; speedup vs baseline: 1.0916x; 1.0916x over previous
//
#include <hip/hip_runtime.h>
#include <math.h>

#define R_ROIS 2000
#define NOBJ   21
#define NACT   27
#define HUMAN  14
#define CFEAT  512
#define HF     38
#define WF     50
#define DFEAT  (CFEAT*7*7)   // 25088
#define H1DIM  4096
#define NC     4096
// W1: 25088 rows = 512 chunks x 49 rows; grid(512,2) = 1024 blocks = 4/CU exact
#define NP1    512
#define ROWS1  49
// W2: 4096 rows = 256 chunks x 16 rows; grid(256,2) = 512 blocks = 2/CU exact
#define NP2    256
#define ROWS2  16

// ---- ws layout (float offsets) ----
#define WS_KEPT   0                       // 20*4 kept boxes (feature coords, yxyx)
#define WS_FEAT   128                     // 25088
#define WS_P1     25344                   // 512*4096 partials (W1)
#define WS_P1B    (WS_P1 + NP1*NC)        // 16*4096
#define WS_H1R    (WS_P1B + 16*NC)        // 4096
#define WS_P2     (WS_H1R + NC)           // 256*4096 partials (W2)
#define WS_P2B    (WS_P2 + NP2*NC)        // 8*4096
#define WS_FC7R   (WS_P2B + 8*NC)         // 4096
#define WS_LOC    (WS_FC7R + NC)          // 4
#define WS_ACT    (WS_LOC + 4)            // 27

// NMS thresh 0.0 => keep exactly the top-softmax-prob box per class.
// One block per class 1..20: argmax_r (score - logZ), decode+clip that box.
__global__ void k_class_top(const float* __restrict__ scores,
                            const float* __restrict__ off, const float* __restrict__ rois,
                            const int* __restrict__ imgshape, float* __restrict__ kept_box) {
    int cls = blockIdx.x + 1;  // class channel 1..20 -> label cls-1
    __shared__ float sval[256];
    __shared__ int   sidx[256];
    float best = -1e30f; int bidx = 0x7fffffff;
    for (int r = threadIdx.x; r < R_ROIS; r += 256) {
        const float* s = scores + r * NOBJ;
        float m = s[0];
        #pragma unroll
        for (int c = 1; c < NOBJ; ++c) m = fmaxf(m, s[c]);
        float sum = 0.f;
        #pragma unroll
        for (int c = 0; c < NOBJ; ++c) sum += expf(s[c] - m);
        float v = s[cls] - (m + logf(sum));   // log prob; monotone in prob
        if (v > best) { best = v; bidx = r; }
    }
    sval[threadIdx.x] = best; sidx[threadIdx.x] = bidx;
    __syncthreads();
    for (int s = 128; s > 0; s >>= 1) {
        if (threadIdx.x < s) {
            float ov = sval[threadIdx.x + s]; int oi = sidx[threadIdx.x + s];
            if (ov > sval[threadIdx.x] ||
                (ov == sval[threadIdx.x] && oi < sidx[threadIdx.x])) {
                sval[threadIdx.x] = ov; sidx[threadIdx.x] = oi;
            }
        }
        __syncthreads();
    }
    if (threadIdx.x == 0) {
        int r = sidx[0];
        float Himg = (float)imgshape[0], Wimg = (float)imgshape[1];
        float sy = (float)HF / Himg, sx = (float)WF / Wimg;
        float y1 = rois[r*4+0]*sy, x1 = rois[r*4+1]*sx;
        float y2 = rois[r*4+2]*sy, x2 = rois[r*4+3]*sx;
        float dy = off[r*(NOBJ*4) + cls*4+0] * 0.1f;
        float dx = off[r*(NOBJ*4) + cls*4+1] * 0.1f;
        float dh = off[r*(NOBJ*4) + cls*4+2] * 0.2f;
        float dw = off[r*(NOBJ*4) + cls*4+3] * 0.2f;
        float h = y2 - y1, w = x2 - x1;
        float cy = y1 + 0.5f*h, cx = x1 + 0.5f*w;
        float cy2 = dy*h + cy, cx2 = dx*w + cx;
        float h2 = expf(dh)*h, w2 = expf(dw)*w;
        float by1 = fminf(fmaxf(cy2 - 0.5f*h2, 0.f), (float)HF);
        float bx1 = fminf(fmaxf(cx2 - 0.5f*w2, 0.f), (float)WF);
        float by2 = fminf(fmaxf(cy2 + 0.5f*h2, 0.f), (float)HF);
        float bx2 = fminf(fmaxf(cx2 + 0.5f*w2, 0.f), (float)WF);
        int l = cls - 1;
        kept_box[l*4+0] = by1; kept_box[l*4+1] = bx1;
        kept_box[l*4+2] = by2; kept_box[l*4+3] = bx2;
    }
}

// chainer RoIPooling2D on the human box (feature coords scaled AGAIN by 1/16 — quirk preserved)
__global__ void k_roipool(const float* __restrict__ x, const float* __restrict__ kept_box,
                          float* __restrict__ feat) {
    int idx = blockIdx.x * blockDim.x + threadIdx.x;
    if (idx >= DFEAT) return;
    float y1 = kept_box[HUMAN*4+0], x1 = kept_box[HUMAN*4+1];
    float y2 = kept_box[HUMAN*4+2], x2 = kept_box[HUMAN*4+3];
    int xmin = (int)rintf(x1 * 0.0625f);   // jnp.round = round-half-even = rintf
    int ymin = (int)rintf(y1 * 0.0625f);
    int xmax = (int)rintf(x2 * 0.0625f);
    int ymax = (int)rintf(y2 * 0.0625f);
    float rw = (float)max(xmax - xmin + 1, 1);
    float rh = (float)max(ymax - ymin + 1, 1);
    int c = idx / 49, rem = idx % 49, pi = rem / 7, pj = rem % 7;
    int hs  = min(max(ymin + (int)floorf((float)pi * rh / 7.f), 0), HF);
    int he  = min(max(ymin + (int)ceilf((float)(pi+1) * rh / 7.f), 0), HF);
    int wss = min(max(xmin + (int)floorf((float)pj * rw / 7.f), 0), WF);
    int we  = min(max(xmin + (int)ceilf((float)(pj+1) * rw / 7.f), 0), WF);
    float m = -1e30f;
    for (int rr = hs; rr < he; ++rr)
        for (int cc = wss; cc < we; ++cc)
            m = fmaxf(m, x[c*(HF*WF) + rr*WF + cc]);
    feat[idx] = (m <= -5e29f) ? 0.f : m;
}

// Stage A of v^T @ W (W row-major [nrows, NC]). grid.x = row chunks (ROWS each),
// grid.y = 2 (2048-col tiles). 8 accumulators -> 8 independent 16B loads in
// flight per unroll group. Partials (conflict-free) to ws.
template<int ROWS, int UNROLL>
__global__ __launch_bounds__(256)
void k_mv_part(const float* __restrict__ W, const float* __restrict__ vin,
               float* __restrict__ part) {
    __shared__ float sv[ROWS];
    int row0 = blockIdx.x * ROWS;
    int col0 = blockIdx.y * 2048 + threadIdx.x * 4;
    for (int i = threadIdx.x; i < ROWS; i += 256) sv[i] = vin[row0 + i];
    __syncthreads();
    float a0=0.f,a1=0.f,a2=0.f,a3=0.f,b0=0.f,b1=0.f,b2=0.f,b3=0.f;
    const float4* Wv = (const float4*)W;
    long base = ((long)row0 * NC + col0) >> 2;
    #pragma unroll UNROLL
    for (int i = 0; i < ROWS; ++i) {
        float f = sv[i];
        float4 w0 = Wv[base + (long)i * (NC/4)];
        float4 w1 = Wv[base + (long)i * (NC/4) + 256];  // +1024 cols
        a0 += f*w0.x; a1 += f*w0.y; a2 += f*w0.z; a3 += f*w0.w;
        b0 += f*w1.x; b1 += f*w1.y; b2 += f*w1.z; b3 += f*w1.w;
    }
    float4* p = (float4*)(part + (long)blockIdx.x * NC + col0);
    p[0]   = make_float4(a0, a1, a2, a3);
    p[256] = make_float4(b0, b1, b2, b3);
}

// Reduction stage 1: block (cx, py) sums PCHUNK parts for its 256 cols.
template<int PCHUNK>
__global__ __launch_bounds__(256)
void k_red_a(const float* __restrict__ part, float* __restrict__ part2) {
    int c = blockIdx.x * 256 + threadIdx.x;
    long base = (long)blockIdx.y * PCHUNK * NC + c;
    float s = 0.f;
    #pragma unroll 8
    for (int p = 0; p < PCHUNK; ++p) s += part[base + (long)p * NC];
    part2[blockIdx.y * NC + c] = s;
}

// Reduction stage 2: sum NP2B partials + bias + relu.
__global__ void k_red_b(const float* __restrict__ part2, const float* __restrict__ bias,
                        float* __restrict__ vout, int np) {
    int c = blockIdx.x * 256 + threadIdx.x;
    float s = 0.f;
    for (int p = 0; p < np; ++p) s += part2[p * NC + c];
    vout[c] = fmaxf(s + bias[c], 0.f);
}

// small heads: 31 blocks, block k -> dot(fc7r, col k of W_loc/W_act) + bias
__global__ void k_heads(const float* __restrict__ fc7r,
                        const float* __restrict__ W_loc, const float* __restrict__ b_loc,
                        const float* __restrict__ W_act, const float* __restrict__ b_act,
                        float* __restrict__ loc_out, float* __restrict__ act_out) {
    int k = blockIdx.x;  // 0..30
    __shared__ float red[256];
    float sum = 0.f;
    if (k < 4) {
        for (int i = threadIdx.x; i < H1DIM; i += 256) sum += fc7r[i] * W_loc[i*4 + k];
    } else {
        int j = k - 4;
        for (int i = threadIdx.x; i < H1DIM; i += 256) sum += fc7r[i] * W_act[i*NACT + j];
    }
    red[threadIdx.x] = sum; __syncthreads();
    for (int s = 128; s > 0; s >>= 1) {
        if (threadIdx.x < s) red[threadIdx.x] += red[threadIdx.x + s];
        __syncthreads();
    }
    if (threadIdx.x == 0) {
        if (k < 4) loc_out[k] = red[0] + b_loc[k];
        else       act_out[k-4] = red[0] + b_act[k-4];
    }
}

// gaussian object pick over the 19 kept non-human boxes + write all 36 outputs
__global__ void k_final(const float* __restrict__ kept_box, const float* __restrict__ loc_out,
                        const float* __restrict__ act_out, const int* __restrict__ imgshape,
                        float* __restrict__ out) {
    if (threadIdx.x != 0 || blockIdx.x != 0) return;
    float hb0 = kept_box[HUMAN*4+0], hb1 = kept_box[HUMAN*4+1];
    float hb2 = kept_box[HUMAN*4+2], hb3 = kept_box[HUMAN*4+3];
    float h4w = hb3 - hb1, h4h = hb2 - hb0;
    float h4x = 0.5f * h4w, h4y = 0.5f * h4h;
    float hw = fmaxf(h4w, 1e-3f), hh = fmaxf(h4h, 1e-3f);
    float l0 = loc_out[0], l1 = loc_out[1], l2 = loc_out[2], l3 = loc_out[3];
    float muw = l3 - l1, muh = l2 - l0;
    float mux = 0.5f * muw, muy = 0.5f * muh;
    float bestg = -2.f; int bl = 0;
    for (int l = 0; l < 20; ++l) {
        if (l == HUMAN) continue;
        float b0 = kept_box[l*4+0], b1 = kept_box[l*4+1];
        float b2 = kept_box[l*4+2], b3 = kept_box[l*4+3];
        float cw = fmaxf(b3 - b1, 1e-3f), ch = fmaxf(b2 - b0, 1e-3f);
        float c0 = 0.5f * (b3 - b1), c1 = 0.5f * (b2 - b0);
        float d0 = (c0 - h4x) / hw - mux;
        float d1 = (c1 - h4y) / hh - muy;
        float d2 = logf(cw / hw) - muw;
        float d3 = logf(ch / hh) - muh;
        float g = expf(-(d0*d0 + d1*d1 + d2*d2 + d3*d3) / (2.f * 0.3f * 0.3f));
        if (g > bestg) { bestg = g; bl = l; }  // ascending l == flatten-order tie-break
    }
    float Himg = (float)imgshape[0], Wimg = (float)imgshape[1];
    float iy = Himg / (float)HF, ix = Wimg / (float)WF;
    out[0] = hb0 * iy; out[1] = hb1 * ix; out[2] = hb2 * iy; out[3] = hb3 * ix;
    out[4] = kept_box[bl*4+0] * iy; out[5] = kept_box[bl*4+1] * ix;
    out[6] = kept_box[bl*4+2] * iy; out[7] = kept_box[bl*4+3] * ix;
    for (int j = 0; j < NACT; ++j) out[8+j] = act_out[j];
    out[35] = (float)HF / Himg;
}

extern "C" void kernel_launch(void* const* d_in, const int* in_sizes, int n_in,
                              void* d_out, int out_size, void* d_ws, size_t ws_size,
                              hipStream_t stream) {
    const float* x           = (const float*)d_in[0];
    const float* pred_scores = (const float*)d_in[1];
    const float* pred_off    = (const float*)d_in[2];
    const float* rois        = (const float*)d_in[3];
    const int*   imgshape    = (const int*)d_in[4];
    const float* W1          = (const float*)d_in[5];
    const float* b1          = (const float*)d_in[6];
    const float* W2          = (const float*)d_in[7];
    const float* b2          = (const float*)d_in[8];
    const float* W_loc       = (const float*)d_in[9];
    const float* b_loc       = (const float*)d_in[10];
    const float* W_act       = (const float*)d_in[11];
    const float* b_act       = (const float*)d_in[12];
    float* out = (float*)d_out;

    float* ws   = (float*)d_ws;
    float* kept = ws + WS_KEPT;
    float* feat = ws + WS_FEAT;
    float* p1   = ws + WS_P1;
    float* p1b  = ws + WS_P1B;
    float* h1r  = ws + WS_H1R;
    float* p2   = ws + WS_P2;
    float* p2b  = ws + WS_P2B;
    float* fc7r = ws + WS_FC7R;
    float* loco = ws + WS_LOC;
    float* acto = ws + WS_ACT;

    k_class_top<<<20, 256, 0, stream>>>(pred_scores, pred_off, rois, imgshape, kept);
    k_roipool<<<(DFEAT + 255) / 256, 256, 0, stream>>>(x, kept, feat);
    // W1 matvec: 1024 blocks (4/CU exact), then 512-deep reduce in two stages
    k_mv_part<ROWS1, 7><<<dim3(NP1, 2), 256, 0, stream>>>(W1, feat, p1);
    k_red_a<32><<<dim3(16, 16), 256, 0, stream>>>(p1, p1b);
    k_red_b<<<16, 256, 0, stream>>>(p1b, b1, h1r, 16);
    // W2 matvec: 512 blocks (2/CU exact), 256-deep reduce in two stages
    k_mv_part<ROWS2, 8><<<dim3(NP2, 2), 256, 0, stream>>>(W2, h1r, p2);
    k_red_a<32><<<dim3(16, 8), 256, 0, stream>>>(p2, p2b);
    k_red_b<<<16, 256, 0, stream>>>(p2b, b2, fc7r, 8);
    k_heads<<<31, 256, 0, stream>>>(fc7r, W_loc, b_loc, W_act, b_act, loco, acto);
    k_final<<<1, 64, 0, stream>>>(kept, loco, acto, imgshape, out);
}